// Round 1
// 7781.137 us; speedup vs baseline: 1.1525x; 1.1525x over previous
//
#include <hip/hip_runtime.h>
#include <math.h>

// B=16, T=8, C=3, H=W=14, HID=32, IND=16, N=3
// hidden[n]: (16,32,14,14) = 100352 floats

// -------------------------------------------------------------------------
// Full-K accumulating GEMV: out[b*N + n] = bias[n] + dot(act[b,:K], W[n,:K])
// grid.x = N/16, block = 256 threads (4 waves). Wave w owns rows n0+4w..+3.
// K walked in 256-float chunks; act chunk staged once per block into
// double-buffered LDS (1 barrier/chunk), shared by all 4 waves.
// Lane owns 4 k's (off = lane*4). Accumulators held in registers across the
// whole K loop; the 64-lane butterfly reduction runs ONCE per block (vs once
// per row*slice before), and results are stored directly with bias.
// Requires N % 16 == 0, K % 4 == 0.
// -------------------------------------------------------------------------
#define GEMV_CHUNK 256

__global__ __launch_bounds__(256) void gemv_full(
    const float* __restrict__ act, int act_stride,
    const float* __restrict__ W, const float* __restrict__ bias,
    float* __restrict__ out, int N, int K)
{
    __shared__ float lact[2][16 * GEMV_CHUNK];   // 2 x 16KB
    const int tid  = threadIdx.x;
    const int wave = tid >> 6;
    const int lane = tid & 63;
    const int n0   = blockIdx.x * 16 + wave * 4;
    const int off  = lane << 2;                  // this lane's 4 k's in chunk
    const float4 z4 = make_float4(0.f, 0.f, 0.f, 0.f);

    float acc[4][16];
#pragma unroll
    for (int r = 0; r < 4; ++r)
#pragma unroll
        for (int b = 0; b < 16; ++b) acc[r][b] = 0.f;

    const float* wr0 = W + (size_t)n0 * K;

    int p = 0;
    for (int kb = 0; kb < K; kb += GEMV_CHUNK) {
        const int len = min(GEMV_CHUNK, K - kb);     // multiple of 4

        // stage act[0:16][kb:kb+256] -> lact[p]; zero-fill past len.
        // pass covers 1024 floats; wave reads one contiguous 1KB row segment.
#pragma unroll
        for (int pass = 0; pass < 4; ++pass) {
            const int i = (pass << 10) + (tid << 2);
            const int b = i >> 8, k = i & 255;
            float4 v = (k < len)
                ? *(const float4*)(act + (size_t)b * act_stride + kb + k) : z4;
            *(float4*)&lact[p][i] = v;
        }

        // this chunk's weight fragments (issued before the barrier so the
        // vmcnt drain at the barrier covers them too)
        const bool g = off < len;
        float4 w[4];
#pragma unroll
        for (int r = 0; r < 4; ++r)
            w[r] = g ? *(const float4*)(wr0 + (size_t)r * K + kb + off) : z4;

        __syncthreads();   // lact[p] staged; previous buffer free for reuse

        // process b in halves of 8 to cap live float4 registers
#pragma unroll
        for (int h2 = 0; h2 < 2; ++h2) {
            float4 la[8];
#pragma unroll
            for (int b = 0; b < 8; ++b)
                la[b] = *(const float4*)&lact[p][((h2 * 8 + b) << 8) + off];
#pragma unroll
            for (int r = 0; r < 4; ++r)
#pragma unroll
                for (int b = 0; b < 8; ++b) {
                    float v = acc[r][h2 * 8 + b];
                    v = fmaf(w[r].x, la[b].x, v);
                    v = fmaf(w[r].y, la[b].y, v);
                    v = fmaf(w[r].z, la[b].z, v);
                    v = fmaf(w[r].w, la[b].w, v);
                    acc[r][h2 * 8 + b] = v;
                }
        }
        p ^= 1;
    }

    // one butterfly per block, direct store with bias
#pragma unroll
    for (int r = 0; r < 4; ++r) {
        const float bv = bias[n0 + r];
#pragma unroll
        for (int b = 0; b < 16; ++b) {
            float v = acc[r][b];
#pragma unroll
            for (int m = 1; m < 64; m <<= 1) v += __shfl_xor(v, m, 64);
            if (lane == 0) out[(size_t)b * N + n0 + r] = v + bv;
        }
    }
}

// MaxPool 3x3 s1 p1 on (16,32,14,14) -> flat (16,6272)
__global__ __launch_bounds__(256) void maxpool3_k(const float* __restrict__ h,
                                                  float* __restrict__ out)
{
    int i = blockIdx.x * 256 + threadIdx.x;
    if (i >= 16 * 32 * 196) return;
    int p = i % 196;
    int y = p / 14, x = p - y * 14;
    const float* base = h + (i - p);
    int y0 = max(y - 1, 0), y1 = min(y + 1, 13);
    int x0 = max(x - 1, 0), x1 = min(x + 1, 13);
    float m = -INFINITY;
    for (int yy = y0; yy <= y1; ++yy)
        for (int xc = x0; xc <= x1; ++xc)
            m = fmaxf(m, base[yy * 14 + xc]);
    out[i] = m;
}

// Gate conv: sigmoid(conv3x3(cat[bu(16ch), h(32ch)] (+ td), Wg, bg))
template<bool HAS_TD>
__global__ __launch_bounds__(256) void gate_conv(
    const float* __restrict__ bu, const float* __restrict__ h,
    const float* __restrict__ td,
    const float* __restrict__ Wg, const float* __restrict__ bg,
    float* __restrict__ rh, float* __restrict__ z)
{
    int i = blockIdx.x * 256 + threadIdx.x;
    if (i >= 16 * 64 * 196) return;
    int p = i % 196;
    int rest = i / 196;
    int o = rest & 63;
    int b = rest >> 6;
    int y = p / 14, x = p - y * 14;
    int ky0 = (y == 0) ? 1 : 0, ky1 = (y == 13) ? 2 : 3;
    int kx0 = (x == 0) ? 1 : 0, kx1 = (x == 13) ? 2 : 3;

    float acc = bg[o];
    const float* wb  = Wg + o * 432;
    const float* bub = bu + b * 3136;
    const float* hb  = h  + b * 6272;
    const float* tdb = HAS_TD ? td + b * 9408 : nullptr;

    for (int ci = 0; ci < 48; ++ci) {
        const float* src = (ci < 16) ? (bub + ci * 196) : (hb + (ci - 16) * 196);
        const float* w   = wb + ci * 9;
        const float* tp  = HAS_TD ? (tdb + ci * 196) : nullptr;
        for (int ky = ky0; ky < ky1; ++ky) {
            int q = p + (ky - 1) * 14 - 1;
            for (int kx = kx0; kx < kx1; ++kx) {
                float v = src[q + kx];
                if (HAS_TD) v += tp[q + kx];
                acc += v * w[ky * 3 + kx];
            }
        }
    }
    float g = 1.f / (1.f + expf(-acc));
    if (o < 32) {
        int idx = (b * 32 + o) * 196 + p;
        rh[idx] = g * h[idx];
    } else {
        int idx = (b * 32 + (o - 32)) * 196 + p;
        z[idx] = g;
    }
}

// cand = tanh(conv3x3(cat[bu, rh], Wc, bc)); h = (1-z)*h + z*cand
__global__ __launch_bounds__(256) void cand_conv(
    const float* __restrict__ bu, const float* __restrict__ rh,
    const float* __restrict__ z,
    const float* __restrict__ Wc, const float* __restrict__ bc,
    float* __restrict__ h)
{
    int i = blockIdx.x * 256 + threadIdx.x;
    if (i >= 16 * 32 * 196) return;
    int p = i % 196;
    int rest = i / 196;
    int o = rest & 31;
    int b = rest >> 5;
    int y = p / 14, x = p - y * 14;
    int ky0 = (y == 0) ? 1 : 0, ky1 = (y == 13) ? 2 : 3;
    int kx0 = (x == 0) ? 1 : 0, kx1 = (x == 13) ? 2 : 3;

    float acc = bc[o];
    const float* wb  = Wc + o * 432;
    const float* bub = bu + b * 3136;
    const float* rhb = rh + b * 6272;

    for (int ci = 0; ci < 48; ++ci) {
        const float* src = (ci < 16) ? (bub + ci * 196) : (rhb + (ci - 16) * 196);
        const float* w   = wb + ci * 9;
        for (int ky = ky0; ky < ky1; ++ky) {
            int q = p + (ky - 1) * 14 - 1;
            for (int kx = kx0; kx < kx1; ++kx)
                acc += src[q + kx] * w[ky * 3 + kx];
        }
    }
    float cand = tanhf(acc);
    int idx = (b * 32 + o) * 196 + p;
    float zv = z[idx];
    h[idx] = (1.f - zv) * h[idx] + zv * cand;
}

// Head matmul (small M): out[b,n] = relu?(dot(relu?(in[b]), W[n]) + bias[n])
template<bool RELU_IN, bool RELU_OUT>
__global__ __launch_bounds__(256) void matmul_tn(
    const float* __restrict__ in, int in_stride,
    const float* __restrict__ W, const float* __restrict__ bias,
    float* __restrict__ out, int N, int K)
{
    __shared__ float lds[16 * 512];
    const int tid  = threadIdx.x;
    const int wave = tid >> 6;
    const int lane = tid & 63;
    const int n0   = blockIdx.x * 16 + wave * 4;

    bool rv[4];
    const float* wr[4];
#pragma unroll
    for (int r = 0; r < 4; ++r) {
        rv[r] = (n0 + r) < N;
        wr[r] = W + (size_t)(n0 + r) * K;
    }

    float acc[4][16];
#pragma unroll
    for (int r = 0; r < 4; ++r)
#pragma unroll
        for (int b = 0; b < 16; ++b) acc[r][b] = 0.f;

    for (int k0 = 0; k0 < K; k0 += 512) {
        const int len = min(512, K - k0);
        __syncthreads();
        for (int i = tid; i < 16 * 512; i += 256) {
            const int b = i >> 9, kk = i & 511;
            if (kk < len) {
                float v = in[b * in_stride + k0 + kk];
                if (RELU_IN) v = fmaxf(v, 0.f);
                lds[i] = v;
            }
        }
        __syncthreads();
        for (int kk = lane * 4; kk < len; kk += 256) {
            float4 w[4];
#pragma unroll
            for (int r = 0; r < 4; ++r)
                w[r] = rv[r] ? *(const float4*)(wr[r] + k0 + kk)
                             : make_float4(0.f, 0.f, 0.f, 0.f);
#pragma unroll
            for (int b = 0; b < 16; ++b) {
                const float4 v = *(const float4*)(&lds[(b << 9) + kk]);
#pragma unroll
                for (int r = 0; r < 4; ++r) {
                    acc[r][b] += w[r].x * v.x + w[r].y * v.y +
                                 w[r].z * v.z + w[r].w * v.w;
                }
            }
        }
    }

#pragma unroll
    for (int r = 0; r < 4; ++r) {
        const float brv = rv[r] ? bias[n0 + r] : 0.f;
#pragma unroll
        for (int b = 0; b < 16; ++b) {
            float v = acc[r][b];
#pragma unroll
            for (int o = 32; o > 0; o >>= 1)
                v += __shfl_down(v, o, 64);
            if (lane == 0 && rv[r]) {
                v += brv;
                if (RELU_OUT) v = fmaxf(v, 0.f);
                out[b * N + (n0 + r)] = v;
            }
        }
    }
}

// -------------------------------------------------------------------------
extern "C" void kernel_launch(void* const* d_in, const int* in_sizes, int n_in,
                              void* d_out, int out_size, void* d_ws, size_t ws_size,
                              hipStream_t stream)
{
    (void)in_sizes; (void)n_in; (void)out_size; (void)ws_size;

    const float* x     = (const float*)d_in[0];
    const float* Wg    = (const float*)d_in[1];
    const float* bg    = (const float*)d_in[2];
    const float* Wc    = (const float*)d_in[3];
    const float* bc    = (const float*)d_in[4];
    const float* bu_w[3] = {(const float*)d_in[5], (const float*)d_in[7], (const float*)d_in[9]};
    const float* bu_b[3] = {(const float*)d_in[6], (const float*)d_in[8], (const float*)d_in[10]};
    const float* td_w[2] = {(const float*)d_in[11], (const float*)d_in[13]};
    const float* td_b[2] = {(const float*)d_in[12], (const float*)d_in[14]};
    const float* fc1_w = (const float*)d_in[15];
    const float* fc1_b = (const float*)d_in[16];
    const float* fc2_w = (const float*)d_in[17];
    const float* fc2_b = (const float*)d_in[18];
    float* out = (float*)d_out;

    float* ws     = (float*)d_ws;
    float* hid0   = ws;                  // 100352 each
    float* hid1   = hid0 + 100352;
    float* hid2   = hid1 + 100352;
    float* bu_buf = hid2 + 100352;       // 16*3136
    float* td_buf = bu_buf + 50176;      // 16*9408
    float* rh_buf = td_buf + 150528;     // 16*32*196
    float* z_buf  = rh_buf + 100352;
    float* p1_buf = z_buf + 100352;      // 1600
    float* mpA    = p1_buf + 1600;       // mp(hid0)
    float* mpB    = mpA + 100352;        // mp(hid1)
    float* mpC    = mpB + 100352;        // mp(hid2)

    hipMemsetAsync(ws, 0, 3 * 100352 * sizeof(float), stream);

    // td: N=9408, K=6272 -> grid 588
    auto TD = [&](const float* mp, const float* Wp, const float* bp) {
        gemv_full<<<588, 256, 0, stream>>>(mp, 6272, Wp, bp, td_buf, 9408, 6272);
    };
    // bu: N=3136, K=6272 -> grid 196
    auto BU = [&](const float* mp, const float* Wp, const float* bp) {
        gemv_full<<<196, 256, 0, stream>>>(mp, 6272, Wp, bp, bu_buf, 3136, 6272);
    };

    for (int t = 0; t < 10; ++t) {       // T + N - 1 = 10
        // ---- node 0 ----
        if (t < 8) {
            // bu0: act = x[:,t] read strided straight out of x; N=3136, K=588
            gemv_full<<<196, 256, 0, stream>>>(x + t * 588, 4704, bu_w[0], bu_b[0],
                                               bu_buf, 3136, 588);
            if (t >= 2) {
                // td from hid1 pre-update this t == mp(hid1) computed at t-1 node2 (mpB)
                TD(mpB, td_w[0], td_b[0]);
                gate_conv<true><<<784, 256, 0, stream>>>(bu_buf, hid0, td_buf, Wg, bg, rh_buf, z_buf);
            } else {
                gate_conv<false><<<784, 256, 0, stream>>>(bu_buf, hid0, nullptr, Wg, bg, rh_buf, z_buf);
            }
            cand_conv<<<392, 256, 0, stream>>>(bu_buf, rh_buf, z_buf, Wc, bc, hid0);
        }
        // ---- node 1 (hid0 post-update, hid2 pre-update) ----
        if (t >= 1) {
            if (t < 8) maxpool3_k<<<392, 256, 0, stream>>>(hid0, mpA);
            // (t>=8: hid0 unchanged since t=7 -> mpA still valid)
            BU(mpA, bu_w[1], bu_b[1]);
            const float* wg1 = Wg + 27648;
            const float* bg1 = bg + 64;
            if (t >= 2) {
                maxpool3_k<<<392, 256, 0, stream>>>(hid2, mpC);
                TD(mpC, td_w[1], td_b[1]);
                gate_conv<true><<<784, 256, 0, stream>>>(bu_buf, hid1, td_buf, wg1, bg1, rh_buf, z_buf);
            } else {
                gate_conv<false><<<784, 256, 0, stream>>>(bu_buf, hid1, nullptr, wg1, bg1, rh_buf, z_buf);
            }
            cand_conv<<<392, 256, 0, stream>>>(bu_buf, rh_buf, z_buf, Wc + 13824, bc + 32, hid1);
        }
        // ---- node 2 (hid1 post-update; no td) ----
        if (t >= 1) {
            maxpool3_k<<<392, 256, 0, stream>>>(hid1, mpB);   // also serves node0 td at t+1
            BU(mpB, bu_w[2], bu_b[2]);
            gate_conv<false><<<784, 256, 0, stream>>>(bu_buf, hid2, nullptr,
                                                      Wg + 2 * 27648, bg + 128, rh_buf, z_buf);
            cand_conv<<<392, 256, 0, stream>>>(bu_buf, rh_buf, z_buf, Wc + 2 * 13824, bc + 64, hid2);
        }
    }

    // ---- head ----
    matmul_tn<true, true><<<dim3(7), dim3(256), 0, stream>>>(hid2, 6272, fc1_w, fc1_b, p1_buf, 100, 6272);
    matmul_tn<false, false><<<dim3(1), dim3(256), 0, stream>>>(p1_buf, 100, fc2_w, fc2_b, out, 10, 100);
}